// Round 1
// baseline (5996.992 us; speedup 1.0000x reference)
//
#include <hip/hip_runtime.h>

typedef _Float16 f16;
typedef f16 f16x8 __attribute__((ext_vector_type(8)));
typedef f16 f16x2 __attribute__((ext_vector_type(2)));
typedef float f32x4 __attribute__((ext_vector_type(4)));

#define KLSTM 2048

__device__ inline float fsig(float x) { return 1.f / (1.f + __expf(-x)); }
__device__ inline float ftanh(float x) {
    x = fminf(15.f, fmaxf(-15.f, x));
    float e = __expf(2.f * x);
    return (e - 1.f) / (e + 1.f);
}

// ---------------- one-time conversions ----------------
__global__ __launch_bounds__(256) void k_convert(
    const float* __restrict__ Wih, const float* __restrict__ Whh,
    const float* __restrict__ W1, const float* __restrict__ W2,
    const float* __restrict__ henc,
    f16* __restrict__ wcat, f16* __restrict__ w1t, f16* __restrict__ w2a,
    f16* __restrict__ h16)
{
    const long NW = 2L * 4096 * 2048;
    const long NT = 1024L * 1024;
    const long NA = 512L * 1024;
    const long NH = 64L * 128 * 1024;
    for (long i = (long)blockIdx.x * 256 + threadIdx.x; i < NW + NT + NA + NH;
         i += (long)gridDim.x * 256) {
        if (i < NW) {
            long l = i / (4096L * 2048);
            long r = i % (4096L * 2048);
            int j = (int)(r >> 11), k = (int)(r & 2047);
            float val = (k < 1024) ? Wih[(l * 4096 + j) * 1024 + k]
                                   : Whh[(l * 4096 + j) * 1024 + (k - 1024)];
            wcat[i] = (f16)val;
        } else if (i < NW + NT) {
            long r = i - NW;
            int h = (int)(r >> 10), v = (int)(r & 1023);
            w1t[r] = (f16)W1[(long)v * 1024 + h];
        } else if (i < NW + NT + NA) {
            long r = i - NW - NT;
            int e = (int)(r >> 10), v = (int)(r & 1023);
            w2a[r] = (f16)W2[(long)e * 2048 + v];
        } else {
            long r = i - NW - NT - NA;
            h16[r] = (f16)henc[r];
        }
    }
}

// ---------------- state init ----------------
__global__ __launch_bounds__(256) void k_init(
    const int* __restrict__ tgt, const float* __restrict__ emb,
    const float* __restrict__ oinit, const float* __restrict__ hinit,
    f16* __restrict__ A1_0, f16* __restrict__ A2_0, float* __restrict__ c01)
{
    int idx = blockIdx.x * 256 + threadIdx.x;   // 0 .. 393215
    if (idx < 131072) {                  // A1[0] = [x0 | o_init | h0_init]
        int m = idx >> 11, k = idx & 2047;
        float val;
        if (k < 512)       val = emb[(long)tgt[m] * 512 + k];
        else if (k < 1024) val = oinit[m * 512 + (k - 512)];
        else               val = hinit[m * 1024 + (k - 1024)];
        A1_0[idx] = (f16)val;
    } else if (idx < 262144) {           // A2[0] = [0 | h1_init]
        int r = idx - 131072;
        int m = r >> 11, k = r & 2047;
        A2_0[r] = (f16)((k < 1024) ? 0.f : hinit[(64 + m) * 1024 + (k - 1024)]);
    } else {                             // c = 0
        c01[idx - 262144] = 0.f;
    }
}

// ---------------- sb[b,s] = b1 . h_enc[b,s,:] ----------------
__global__ __launch_bounds__(256) void k_sb(
    const float* __restrict__ b1, const float* __restrict__ henc,
    float* __restrict__ sb)
{
    int bs = blockIdx.x * 256 + threadIdx.x;   // 0..8191
    const float* hr = henc + (long)bs * 1024;
    float a = 0.f;
    for (int k = 0; k < 1024; k += 4) {
        float4 h4 = *(const float4*)(hr + k);
        float4 b4 = *(const float4*)(b1 + k);
        a += h4.x * b4.x + h4.y * b4.y + h4.z * b4.z + h4.w * b4.w;
    }
    sb[bs] = a;
}

// ---------------- generic f16 GEMM: C[M,N] = A[M,1024] * B[N,1024]^T ----------------
// block tile 64(M) x 128(N); 4 waves, wave w -> rows 16w..16w+16
__global__ __launch_bounds__(256) void k_gemm(
    const f16* __restrict__ A, const f16* __restrict__ Bm,
    f16* __restrict__ C, int N)
{
    int nb = N >> 7;
    int bm = blockIdx.x / nb, bn = blockIdx.x % nb;
    int tid = threadIdx.x, w = tid >> 6, lane = tid & 63;
    int quad = lane >> 4, nn = lane & 15;
    const f16* ap = A + (long)(bm * 64 + w * 16 + nn) * 1024 + quad * 8;
    const f16* bp = Bm + (long)(bn * 128 + nn) * 1024 + quad * 8;
    f32x4 acc[8] = {};
    for (int kk = 0; kk < 1024; kk += 32) {
        f16x8 av = *(const f16x8*)(ap + kk);
        #pragma unroll
        for (int t2 = 0; t2 < 8; ++t2) {
            f16x8 bv = *(const f16x8*)(bp + (long)t2 * 16 * 1024 + kk);
            acc[t2] = __builtin_amdgcn_mfma_f32_16x16x32_f16(av, bv, acc[t2], 0, 0, 0);
        }
    }
    #pragma unroll
    for (int t2 = 0; t2 < 8; ++t2)
        #pragma unroll
        for (int r = 0; r < 4; ++r) {
            int m = bm * 64 + w * 16 + quad * 4 + r;
            int col = bn * 128 + t2 * 16 + nn;
            C[(long)m * N + col] = (f16)acc[t2][r];
        }
}

// ---------------- fused LSTM layer: gates GEMM + cell update ----------------
// grid 256 blocks; block b owns hidden units 4b..4b+4 (16 gate cols: n=(u<<2)|g)
__global__ __launch_bounds__(256) void k_lstm(
    const f16* __restrict__ A,      // [64][2048] = [inp | h_prev]
    const f16* __restrict__ W,      // [4096][2048] layer slice, row-major K
    const float* __restrict__ bih, const float* __restrict__ bhh,
    float* __restrict__ c,          // [64][1024] layer slice
    f16* __restrict__ hd0,          // f16 dest (stride 2048), col offset pre-added
    f16* __restrict__ hd1,          // optional second f16 dest (stride 2048)
    float* __restrict__ hfull)      // optional fp32 dest (stride 1024)
{
    int tid = threadIdx.x;
    int w = tid >> 6, lane = tid & 63;
    int quad = lane >> 4, n = lane & 15;
    int g = n & 3, u = n >> 2;
    int ug = (blockIdx.x << 2) + u;          // global hidden unit
    int j = g * 1024 + ug;                   // gate column in [0,4096)
    const f16* ap = A + (long)(w * 16 + n) * KLSTM + quad * 8;
    const f16* bp = W + (long)j * KLSTM + quad * 8;
    f32x4 acc = {0.f, 0.f, 0.f, 0.f};
    #pragma unroll 8
    for (int kk = 0; kk < KLSTM; kk += 32) {
        f16x8 av = *(const f16x8*)(ap + kk);
        f16x8 bv = *(const f16x8*)(bp + kk);
        acc = __builtin_amdgcn_mfma_f32_16x16x32_f16(av, bv, acc, 0, 0, 0);
    }
    float bias = bih[j] + bhh[j];
    int base = lane & ~3;
    #pragma unroll
    for (int r = 0; r < 4; ++r) {
        int m = w * 16 + quad * 4 + r;       // batch row
        float v = acc[r] + bias;
        float act = (g == 2) ? ftanh(v) : fsig(v);
        float ti = __shfl(act, base + 0);
        float tf = __shfl(act, base + 1);
        float tg = __shfl(act, base + 2);
        float to = __shfl(act, base + 3);
        float cold = c[m * 1024 + ug];
        float cn = tf * cold + ti * tg;
        float hn = to * ftanh(cn);
        if (g == 0) {
            c[m * 1024 + ug] = cn;
            hd0[m * KLSTM + ug] = (f16)hn;
            if (hd1) hd1[m * KLSTM + ug] = (f16)hn;
            if (hfull) hfull[m * 1024 + ug] = hn;
        }
    }
}

// ---------------- attention: scores/softmax/Z2 (blocks 0..63) + Z1 (64..191) ----------------
__global__ __launch_bounds__(256) void k_attn(
    const float* __restrict__ h1f,   // [64][1024]
    const f16* __restrict__ P,       // [8192][1024]
    const f16* __restrict__ Q2,      // [8192][512]
    const float* __restrict__ sb,    // [64][128]
    const float* __restrict__ W2,    // [512][2048] fp32
    const float* __restrict__ b2,    // [512]
    float* __restrict__ Z1, float* __restrict__ Z2)
{
    __shared__ float sh1[1024];
    __shared__ float spart[2][128];
    __shared__ float ssc[128];
    __shared__ float sred;
    int tid = threadIdx.x;
    if (blockIdx.x < 64) {
        int m = blockIdx.x;
        ((float4*)sh1)[tid] = ((const float4*)(h1f + m * 1024))[tid];
        __syncthreads();
        int s = tid >> 1, ph = tid & 1;
        const f16* pr = P + ((long)(m * 128 + s)) * 1024 + ph * 512;
        const float* hb = sh1 + ph * 512;
        float a0 = 0.f;
        for (int k = 0; k < 512; k += 8) {
            f16x8 pv = *(const f16x8*)(pr + k);
            #pragma unroll
            for (int j2 = 0; j2 < 8; ++j2) a0 += hb[k + j2] * (float)pv[j2];
        }
        spart[ph][s] = a0;
        __syncthreads();
        if (tid < 128) ssc[tid] = spart[0][tid] + spart[1][tid] + sb[m * 128 + tid];
        __syncthreads();
        if (tid < 64) {
            float v = fmaxf(ssc[tid], ssc[tid + 64]);
            #pragma unroll
            for (int off = 32; off; off >>= 1) v = fmaxf(v, __shfl_down(v, off));
            if (tid == 0) sred = v;
        }
        __syncthreads();
        float mx = sred;
        if (tid < 128) ssc[tid] = __expf(ssc[tid] - mx);
        __syncthreads();
        if (tid < 64) {
            float v = ssc[tid] + ssc[tid + 64];
            #pragma unroll
            for (int off = 32; off; off >>= 1) v += __shfl_down(v, off);
            if (tid == 0) sred = v;
        }
        __syncthreads();
        float inv = 1.f / sred;
        if (tid < 128) ssc[tid] *= inv;
        __syncthreads();
        float z0 = 0.f, z1v = 0.f;
        const f16* q2 = Q2 + (long)m * 128 * 512 + 2 * tid;
        for (int s2 = 0; s2 < 128; ++s2) {
            float a = ssc[s2];
            f16x2 qv = *(const f16x2*)(q2 + (long)s2 * 512);
            z0 += a * (float)qv[0];
            z1v += a * (float)qv[1];
        }
        Z2[m * 512 + 2 * tid] = z0;
        Z2[m * 512 + 2 * tid + 1] = z1v;
    } else {
        int blk = blockIdx.x - 64;           // 0..127 -> 4 cols each
        int mi = tid & 63, eo = tid >> 6;
        int e = blk * 4 + eo;
        const float* hr = h1f + mi * 1024;
        const float* wr = W2 + (long)e * 2048 + 1024;
        float a0 = 0.f;
        for (int k = 0; k < 1024; k += 4) {
            float4 hv = *(const float4*)(hr + k);
            float4 wv = *(const float4*)(wr + k);
            a0 += hv.x * wv.x + hv.y * wv.y + hv.z * wv.z + hv.w * wv.w;
        }
        Z1[mi * 512 + e] = a0 + b2[e];
    }
}

// ---------------- output: o = tanh(Z1+Z2); write d_out + feed next step; x gather ----------------
__global__ __launch_bounds__(256) void k_out(
    const float* __restrict__ Z1, const float* __restrict__ Z2,
    float* __restrict__ out, f16* __restrict__ A1n,
    const int* __restrict__ tgt, const float* __restrict__ emb, int t)
{
    int tid = threadIdx.x;
    if (blockIdx.x < 64) {
        int m = blockIdx.x;
        #pragma unroll
        for (int rep = 0; rep < 2; ++rep) {
            int e = tid + rep * 256;
            float o = ftanh(Z1[m * 512 + e] + Z2[m * 512 + e]);
            out[((long)m * 64 + t) * 512 + e] = o;
            A1n[m * 2048 + 512 + e] = (f16)o;
        }
    } else if (t < 63) {
        int m = blockIdx.x - 64;
        int row = tgt[(t + 1) * 64 + m];
        #pragma unroll
        for (int rep = 0; rep < 2; ++rep) {
            int e = tid + rep * 256;
            A1n[m * 2048 + e] = (f16)emb[(long)row * 512 + e];
        }
    }
}

extern "C" void kernel_launch(void* const* d_in, const int* in_sizes, int n_in,
                              void* d_out, int out_size, void* d_ws, size_t ws_size,
                              hipStream_t stream)
{
    const int*   tgt   = (const int*)d_in[0];
    const float* henc  = (const float*)d_in[1];
    const float* emb   = (const float*)d_in[2];
    const float* oinit = (const float*)d_in[3];
    const float* hinit = (const float*)d_in[4];
    const float* Wih   = (const float*)d_in[5];
    const float* Whh   = (const float*)d_in[6];
    const float* bih   = (const float*)d_in[7];
    const float* bhh   = (const float*)d_in[8];
    const float* W1    = (const float*)d_in[9];
    const float* b1    = (const float*)d_in[10];
    const float* W2    = (const float*)d_in[11];
    const float* b2    = (const float*)d_in[12];
    float* out = (float*)d_out;

    char* ws = (char*)d_ws;
    f16*   wcat = (f16*)(ws + 0);              // [2][4096][2048]
    f16*   P16  = (f16*)(ws + 33554432);       // [8192][1024]
    f16*   Q216 = (f16*)(ws + 50331648);       // [8192][512]
    f16*   h16  = (f16*)(ws + 58720256);       // [8192][1024]
    f16*   w1t  = (f16*)(ws + 75497472);       // [1024][1024]
    f16*   w2a  = (f16*)(ws + 77594624);       // [512][1024]
    f16*   A1   = (f16*)(ws + 78643200);       // [2][64][2048]
    f16*   A2   = (f16*)(ws + 79167488);       // [2][64][2048]
    float* h1f  = (float*)(ws + 79691776);     // [64][1024]
    float* c01  = (float*)(ws + 79953920);     // [2][64][1024]
    float* Z1   = (float*)(ws + 80478208);     // [64][512]
    float* Z2   = (float*)(ws + 80609280);     // [64][512]
    float* sb   = (float*)(ws + 80740352);     // [64][128]

    hipLaunchKernelGGL(k_convert, dim3(4096), dim3(256), 0, stream,
                       Wih, Whh, W1, W2, henc, wcat, w1t, w2a, h16);
    hipLaunchKernelGGL(k_init, dim3(1536), dim3(256), 0, stream,
                       tgt, emb, oinit, hinit, A1, A2, c01);
    hipLaunchKernelGGL(k_sb, dim3(32), dim3(256), 0, stream, b1, henc, sb);
    // P = h_enc @ W1  (scores projection), Q2 = h_enc @ W2a^T (attended projection)
    hipLaunchKernelGGL(k_gemm, dim3(128 * 8), dim3(256), 0, stream, h16, w1t, P16, 1024);
    hipLaunchKernelGGL(k_gemm, dim3(128 * 4), dim3(256), 0, stream, h16, w2a, Q216, 512);

    for (int t = 0; t < 64; ++t) {
        int cur = t & 1, nxt = cur ^ 1;
        f16* A1c = A1 + cur * 131072; f16* A1n = A1 + nxt * 131072;
        f16* A2c = A2 + cur * 131072; f16* A2n = A2 + nxt * 131072;
        // layer 0: A=[x_t|o|h0_prev] -> h0 into A2c[:,0:1024] and A1n[:,1024:2048]
        hipLaunchKernelGGL(k_lstm, dim3(256), dim3(256), 0, stream,
            A1c, wcat, bih, bhh, c01, A2c, A1n + 1024, (float*)nullptr);
        // layer 1: A=[h0|h1_prev] -> h1 into A2n[:,1024:2048] and fp32 h1f
        hipLaunchKernelGGL(k_lstm, dim3(256), dim3(256), 0, stream,
            A2c, wcat + 4096 * 2048, bih + 4096, bhh + 4096, c01 + 64 * 1024,
            A2n + 1024, (f16*)nullptr, h1f);
        hipLaunchKernelGGL(k_attn, dim3(192), dim3(256), 0, stream,
            h1f, P16, Q216, sb, W2, b2, Z1, Z2);
        hipLaunchKernelGGL(k_out, dim3(128), dim3(256), 0, stream,
            Z1, Z2, out, A1n, tgt, emb, t);
    }
}